// Round 4
// baseline (60.590 us; speedup 1.0000x reference)
//
#include <hip/hip_runtime.h>

// Block-mask metadata for flex-attention style sparsity — single fused kernel.
// M = N = 32768 tokens, QB = KB = 128 -> 256 x 256 block mask.
//
// bm[qb][kb] = any(q <= kv && doc[q]==doc[kv]) over the 128x128 tile
//            = 0                        if kb < qb
//            = 1                        if kb == qb  (q==kv pair on diagonal)
//            = docs(qb) ∩ docs(kb) != 0 if kb > qb   (causal always true)
//
// Each workgroup r computes row r (kv side) and column r (q side) of the
// 256x256 block mask on the fly. Block summaries (min/max/uniform/first doc)
// are recomputed per-workgroup (thread t summarizes block t) — 128 KB of
// doc reads per workgroup, fully L2/L3 resident, cheaper than a second
// kernel launch + workspace round-trip.
//
// Outputs (flat int32, reference return order):
//   [0,256)        kv_num_blocks   row sums
//   [256,65792)    kv_indices      per-row stable-desc argsort of {0,1}
//   [65792,66048)  q_num_blocks    column sums
//   [66048,131584) q_indices       per-col stable-desc argsort
//   [131584..5]    kv_block_size=128, q_block_size=128

#define NBLK 256   // blocks per side
#define TOK  128   // tokens per block

// bm value for tile (qb, kb); O(1) fast paths; generic fallback never taken
// for the fixed setup_inputs (every 128-block is doc-uniform).
__device__ __forceinline__ int bm_val(int qb, int kb, const int4* S,
                                      const int* __restrict__ doc) {
    if (kb < qb) return 0;
    if (kb == qb) return 1;
    int4 a = S[qb], b = S[kb];
    if (a.y < b.x || b.y < a.x) return 0;          // doc ranges disjoint
    if (a.z && b.z) return (a.w == b.w) ? 1 : 0;   // both uniform
    for (int i = 0; i < TOK; ++i) {                // generic fallback
        int dq = doc[qb * TOK + i];
        for (int j = 0; j < TOK; ++j)
            if (dq == doc[kb * TOK + j]) return 1;
    }
    return 0;
}

__global__ __launch_bounds__(256) void fused_mask_kernel(
        const int* __restrict__ doc, int* __restrict__ out) {
    const int r = blockIdx.x;      // 0..255: row r AND column r
    const int t = threadIdx.x;     // 0..255

    __shared__ int4 S[NBLK];
    __shared__ int wsum[4];

    // ---- per-block summary: thread t reduces block t (32 x int4) ----
    {
        const int4* p = (const int4*)(doc + t * TOK);
        int4 v = p[0];
        int first = v.x;
        int mn = min(min(v.x, v.y), min(v.z, v.w));
        int mx = max(max(v.x, v.y), max(v.z, v.w));
#pragma unroll
        for (int i = 1; i < TOK / 4; ++i) {
            v = p[i];
            mn = min(mn, min(min(v.x, v.y), min(v.z, v.w)));
            mx = max(mx, max(max(v.x, v.y), max(v.z, v.w)));
        }
        S[t] = make_int4(mn, mx, (mn == mx) ? 1 : 0, first);
    }
    __syncthreads();

    int* kvn = out;                       // 256
    int* kvi = out + 256;                 // 65536
    int* qn  = out + 256 + 65536;         // 256
    int* qi  = out + 512 + 65536;         // 65536

    const int lane = t & 63;
    const int wv   = t >> 6;

    // ---------- row r: kv_num_blocks / kv_indices ----------
    {
        int v = bm_val(r, t, S, doc);
        unsigned long long m = __ballot(v != 0);
        int prew = __popcll(m & ((1ULL << lane) - 1ULL));
        int wtot = __popcll(m);
        if (lane == 0) wsum[wv] = wtot;
        __syncthreads();
        int base = 0;
        for (int i = 0; i < wv; ++i) base += wsum[i];
        int total = wsum[0] + wsum[1] + wsum[2] + wsum[3];
        int pre = base + prew;                       // ones strictly before t
        int rank = v ? pre : (total + (t - pre));    // stable desc argsort rank
        kvi[r * NBLK + rank] = t;
        if (t == 0) kvn[r] = total;
        __syncthreads();   // wsum reused below
    }

    // ---------- column r: q_num_blocks / q_indices ----------
    {
        int v = bm_val(t, r, S, doc);
        unsigned long long m = __ballot(v != 0);
        int prew = __popcll(m & ((1ULL << lane) - 1ULL));
        int wtot = __popcll(m);
        if (lane == 0) wsum[wv] = wtot;
        __syncthreads();
        int base = 0;
        for (int i = 0; i < wv; ++i) base += wsum[i];
        int total = wsum[0] + wsum[1] + wsum[2] + wsum[3];
        int pre = base + prew;
        int rank = v ? pre : (total + (t - pre));
        qi[r * NBLK + rank] = t;
        if (t == 0) qn[r] = total;
    }

    if (r == 0 && t == 0) {
        out[512 + 2 * 65536 + 0] = 128;   // kv_block_size
        out[512 + 2 * 65536 + 1] = 128;   // q_block_size
    }
}

extern "C" void kernel_launch(void* const* d_in, const int* in_sizes, int n_in,
                              void* d_out, int out_size, void* d_ws, size_t ws_size,
                              hipStream_t stream) {
    // d_in[0] = x (8x128 f32, unused), d_in[1] = document_id (int32[32768])
    const int* doc = (const int*)d_in[1];
    int* out = (int*)d_out;

    hipLaunchKernelGGL(fused_mask_kernel, dim3(NBLK), dim3(256), 0, stream,
                       doc, out);
}